// Round 1
// 179.369 us; speedup vs baseline: 1.1379x; 1.1379x over previous
//
#include <hip/hip_runtime.h>
#include <math.h>

static constexpr int TB = 64;   // batch
static constexpr int LL = 32;   // labels
static constexpr int SS = 256;  // max target length
static constexpr int STRIDE_T = TB * LL;  // floats per time step (2048)

// ---- workspace layout (floats per batch) --------------------------------
static constexpr int OF_FWD  = 0;                 // 33: alpha[32] + K
static constexpr int OF_BWD  = 33;                // 33: v[32] + K
static constexpr int OF_MA   = 66;                // 32 cols x 33
static constexpr int OF_MB   = 66 + 32 * 33;      // 1122
static constexpr int OF_FACF = 1122 + 32 * 33;    // 2178: 256 vals + 64 scales
static constexpr int OF_FACB = 2178 + 320;        // 2498: 256 vals + 64 scales
static constexpr int WSB     = 2818;              // per-batch stride

#define LN2F 0.69314718055994530942f
#define NEGF (-1e30f)
#define SBAR() __builtin_amdgcn_sched_barrier(0)

// ---- DPP / cross-lane helpers ------------------------------------------
template<int CTL>
__device__ __forceinline__ float dpp_f(float x, float oldv) {
  return __int_as_float(__builtin_amdgcn_update_dpp(
      __float_as_int(oldv), __float_as_int(x), CTL, 0xF, 0xF, false));
}
template<int M>
__device__ __forceinline__ int rot_i(int x) {
  return __builtin_amdgcn_update_dpp(0, x, 0x120 + M, 0xF, 0xF, false); // row_ror:M
}

typedef unsigned uint2v __attribute__((ext_vector_type(2)));
__device__ __forceinline__ float xsum16(float x) {  // x[l] + x[l^16]
  uint2v r = __builtin_amdgcn_permlane16_swap(__float_as_uint(x), __float_as_uint(x), false, false);
  return __uint_as_float(r.x) + __uint_as_float(r.y);
}
__device__ __forceinline__ float xsum32(float x) {  // x[l] + x[l^32]
  uint2v r = __builtin_amdgcn_permlane32_swap(__float_as_uint(x), __float_as_uint(x), false, false);
  return __uint_as_float(r.x) + __uint_as_float(r.y);
}
__device__ __forceinline__ float bperm(int addr, float src) {  // pull lane addr>>2
  return __int_as_float(__builtin_amdgcn_ds_bpermute(addr, __float_as_int(src)));
}

// Self-calibrating coefficient load (rot_i matches row_ror:M exactly)
template<int M>
struct Calib {
  __device__ static __forceinline__ void run(const float* trans, int lam, int i, float* Ec) {
    Ec[M] = __expf(trans[i * LL + rot_i<M>(lam)]);
    Calib<M + 1>::run(trans, lam, i, Ec);
  }
};
template<> struct Calib<16> {
  __device__ static __forceinline__ void run(const float*, int, int, float*) {}
};
// Transposed variant: coefficient trans[rot(lam)][i]  (M^T matvec)
template<int M>
struct CalibT {
  __device__ static __forceinline__ void run(const float* trans, int lam, int i, float* Ec) {
    Ec[M] = __expf(trans[rot_i<M>(lam) * LL + i]);
    CalibT<M + 1>::run(trans, lam, i, Ec);
  }
};
template<> struct CalibT<16> {
  __device__ static __forceinline__ void run(const float*, int, int, float*) {}
};

// ---- fused rotate-multiply asm (1 instr per term) -----------------------
#define ROT_MUL(DST, SRC, COEF, ROT) \
  asm("v_mul_f32_dpp %0, %1, %2 row_ror:" #ROT " row_mask:0xf bank_mask:0xf" \
      : "=v"(DST) : "v"(SRC), "v"(COEF))
#define ROT_FMAC(ACC, SRC, COEF, ROT) \
  asm("v_fmac_f32_dpp %0, %1, %2 row_ror:" #ROT " row_mask:0xf bank_mask:0xf" \
      : "+v"(ACC) : "v"(SRC), "v"(COEF))

// matvec over 16-lane rows: part = sum_M EC[M] * rot_M(A); 4 indep chains
#define STEP16(EC) { \
  float a0 = EC[0] * A, a1, a2, a3; \
  ROT_MUL(a1, A, EC[1], 1); ROT_MUL(a2, A, EC[2], 2); ROT_MUL(a3, A, EC[3], 3); \
  ROT_FMAC(a0, A, EC[4], 4);  ROT_FMAC(a1, A, EC[5], 5); \
  ROT_FMAC(a2, A, EC[6], 6);  ROT_FMAC(a3, A, EC[7], 7); \
  ROT_FMAC(a0, A, EC[8], 8);  ROT_FMAC(a1, A, EC[9], 9); \
  ROT_FMAC(a2, A, EC[10], 10); ROT_FMAC(a3, A, EC[11], 11); \
  ROT_FMAC(a0, A, EC[12], 12); ROT_FMAC(a1, A, EC[13], 13); \
  ROT_FMAC(a2, A, EC[14], 14); ROT_FMAC(a3, A, EC[15], 15); \
  part = (a0 + a1) + (a2 + a3); }

// ---- staging: 4 coalesced loads stage rows t..t+7 (2 rows/instr) --------
#define LDBLK(R, TBASE) { \
  _Pragma("unroll") for (int k = 0; k < 4; ++k) { \
    int tt = (TBASE) + 2 * k + rowoff; tt = tt > lenm1 ? lenm1 : tt; \
    R[k] = gpl[(size_t)tt * STRIDE_T]; } \
  SBAR(); }
// descending variant: clamp both ends
#define LDBLKD(R, TBASE) { \
  _Pragma("unroll") for (int k = 0; k < 4; ++k) { \
    int tt = (TBASE) + 2 * k + rowoff; \
    tt = tt < 0 ? 0 : (tt > lenm1 ? lenm1 : tt); \
    R[k] = gpl[(size_t)tt * STRIDE_T]; } \
  SBAR(); }

// ======================= FCC ============================================

#define FCC_RENORM() { \
  unsigned uu = (unsigned)__builtin_amdgcn_readfirstlane((int)__float_as_uint(A)); \
  int ex = (int)((uu >> 23) & 255) - 127; \
  A = ldexpf(A, -ex); Kt += ex; }

#define FCC_BLOCK8(R) { \
  float eb[8]; \
  _Pragma("unroll") for (int q = 0; q < 8; ++q) { \
    float raw = bperm((q & 1) ? adO : adE, R[q >> 1]); \
    eb[q] = __expf(raw); } \
  { float part; STEP16(Ec1); A = eb[0] * xsum16(part); } \
  { float part; STEP16(Ec2); A = eb[1] * xsum32(part); } \
  { float part; STEP16(Ec1); A = eb[2] * xsum16(part); } \
  { float part; STEP16(Ec2); A = eb[3] * xsum32(part); } \
  { float part; STEP16(Ec1); A = eb[4] * xsum16(part); } \
  { float part; STEP16(Ec2); A = eb[5] * xsum32(part); } \
  { float part; STEP16(Ec1); A = eb[6] * xsum16(part); } \
  { float part; STEP16(Ec2); A = eb[7] * xsum32(part); } \
  FCC_RENORM(); }

// backward (transpose) block: consumes rows TBASE+7 .. TBASE in that order;
// emission multiplies BEFORE the transposed matvec.
#define FCC_BWDBLK8(R) { \
  float eb[8]; \
  _Pragma("unroll") for (int q = 0; q < 8; ++q) { \
    float raw = bperm((q & 1) ? adO : adE, R[q >> 1]); \
    eb[q] = __expf(raw); } \
  { A *= eb[7]; float part; STEP16(E1T); A = xsum16(part); } \
  { A *= eb[6]; float part; STEP16(E2T); A = xsum32(part); } \
  { A *= eb[5]; float part; STEP16(E1T); A = xsum16(part); } \
  { A *= eb[4]; float part; STEP16(E2T); A = xsum32(part); } \
  { A *= eb[3]; float part; STEP16(E1T); A = xsum16(part); } \
  { A *= eb[2]; float part; STEP16(E2T); A = xsum32(part); } \
  { A *= eb[1]; float part; STEP16(E1T); A = xsum16(part); } \
  { A *= eb[0]; float part; STEP16(E2T); A = xsum32(part); } \
  FCC_RENORM(); }

// ======================= FAC ============================================

#define FAC_STEP(E0, E1, E2, E3) { \
  float ap = dpp_f<0x138>(A3, 0.f); /* wave_shr:1 */ \
  float n0 = (E0) * fmaf(MV0b,  ap, ST[0] * A0); \
  float n1 = (E1) * fmaf(MVl[1], A0, ST[1] * A1); \
  float n2 = (E2) * fmaf(MVl[2], A1, ST[2] * A2); \
  float n3 = (E3) * fmaf(MVl[3], A2, ST[3] * A3); \
  A0 = n0; A1 = n1; A2 = n2; A3 = n3; }

#define FAC_BOUNDARY() { \
  float maxA = fmaxf(fmaxf(A0, A1), fmaxf(A2, A3)); \
  if (maxA > 0.f) { \
    int ex = (int)((__float_as_uint(maxA) >> 23) & 255) - 127; \
    A0 = ldexpf(A0, -ex); A1 = ldexpf(A1, -ex); \
    A2 = ldexpf(A2, -ex); A3 = ldexpf(A3, -ex); \
    m += (float)ex; \
  } \
  float mp = dpp_f<0x138>(m, NEGF); m = (m == NEGF) ? mp : m; \
  mp = dpp_f<0x138>(m, NEGF);       m = (m == NEGF) ? mp : m; \
  mp = dpp_f<0x138>(m, NEGF); \
  float dlt = fminf(mp - m, 50.0f); \
  float Sin = exp2f(dlt); \
  MV0b = MVl[0] * Sin; }

#define FAC_BLOCK8(R) { \
  float E[8][4]; \
  _Pragma("unroll") for (int r = 0; r < 8; ++r) { \
    _Pragma("unroll") for (int j = 0; j < 4; ++j) { \
      float raw = bperm((r & 1) ? adB[j] : adA[j], R[r >> 1]); \
      E[r][j] = __expf(raw); } } \
  _Pragma("unroll") for (int r = 0; r < 8; ++r) \
    FAC_STEP(E[r][0], E[r][1], E[r][2], E[r][3]); \
  FAC_BOUNDARY(); }

// ---- FAC backward (beta) ------------------------------------------------
// beta_{t-1}[s] = E_t[s]*stay[s]*b[s] + E_t[s+1]*move[s+1]*b[s+1]
#define FACB_BOUNDARY() { \
  float maxA = fmaxf(fmaxf(A0, A1), fmaxf(A2, A3)); \
  if (maxA > 0.f) { \
    int ex = (int)((__float_as_uint(maxA) >> 23) & 255) - 127; \
    A0 = ldexpf(A0, -ex); A1 = ldexpf(A1, -ex); \
    A2 = ldexpf(A2, -ex); A3 = ldexpf(A3, -ex); \
    m += (float)ex; \
  } \
  float mp = dpp_f<0x130>(m, NEGF); m = (m == NEGF) ? mp : m; \
  mp = dpp_f<0x130>(m, NEGF);       m = (m == NEGF) ? mp : m; \
  mp = dpp_f<0x130>(m, NEGF); \
  float dlt = fminf(mp - m, 50.0f); \
  MVn3b = MVn[3] * exp2f(dlt); }

#define FACB_BLOCK8(R) { \
  float E[8][4]; \
  _Pragma("unroll") for (int r = 0; r < 8; ++r) { \
    _Pragma("unroll") for (int j = 0; j < 4; ++j) { \
      float raw = bperm((r & 1) ? adB[j] : adA[j], R[r >> 1]); \
      E[r][j] = __expf(raw); } } \
  _Pragma("unroll") for (int i = 0; i < 8; ++i) { \
    const int q = 7 - i; \
    float en3 = dpp_f<0x130>(E[q][0], 0.f); /* wave_shl:1 */ \
    float an  = dpp_f<0x130>(A0, 0.f); \
    float n0 = fmaf(E[q][1] * MVn[0], A1, E[q][0] * ST[0] * A0); \
    float n1 = fmaf(E[q][2] * MVn[1], A2, E[q][1] * ST[1] * A1); \
    float n2 = fmaf(E[q][3] * MVn[2], A3, E[q][2] * ST[2] * A2); \
    float n3 = fmaf(en3 * MVn3b,      an, E[q][3] * ST[3] * A3); \
    A0 = n0; A1 = n1; A2 = n2; A3 = n3; } \
  FACB_BOUNDARY(); }

// ======================= main kernel ====================================

extern "C" __global__ __launch_bounds__(64, 1)
void asg_main(const float* __restrict__ trans, const float* __restrict__ inputs,
              const int* __restrict__ targets, const int* __restrict__ ilen,
              const int* __restrict__ tlen, float* __restrict__ ws) {
  const int l = threadIdx.x;
  const int rowoff = l >> 5;
  const int bid = (int)blockIdx.x;

  // role decode
  int role, b, chunk = 0, col = 0;
  if (bid < TB)            { role = 0; b = bid; }           // FCC fwd vector
  else if (bid < 2 * TB)   { role = 1; b = bid - TB; }      // FCC bwd vector (M^T)
  else if (bid < 3 * TB)   { role = 2; b = bid - 2 * TB; }  // FAC fwd
  else if (bid < 4 * TB)   { role = 3; b = bid - 3 * TB; }  // FAC bwd (beta)
  else {                                                    // FCC basis columns
    int r = bid - 4 * TB;
    int xcd = r & 7, q2 = r >> 3;
    col = q2 & 31;
    int g = (q2 >> 5) * 8 + xcd;   // group in [0,128): XCD-clustered
    b = g & 63; chunk = g >> 6; role = 4;
  }

  const int len = ilen[b];
  const int lenm1 = len - 1;
  const int Lsteps = lenm1;
  const int nch  = (Lsteps / 4) & ~7;        // basis chunk & bwd length (mult of 8)
  const int nfwd = Lsteps - 3 * nch;         // fwd vector length (has tail)
  const float* gpl = inputs + (size_t)b * LL + (l & 31);
  float* P = ws + (size_t)b * WSB;

  if (role == 0 || role == 4) {
    // ---------------- FCC forward-style scan (vector or basis column) ----
    if (role == 0) __builtin_amdgcn_s_setprio(1);
    const int lam1 = l & 31;
    const int lam2 = (l & 15) | ((l >> 5) << 4);
    const int adE = lam2 * 4;
    const int adO = 128 + lam1 * 4;
    float Ec1[16], Ec2[16];
    Ec1[0] = __expf(trans[lam2 * LL + lam1]);
    Ec2[0] = __expf(trans[lam1 * LL + lam2]);
    Calib<1>::run(trans, lam1, lam2, Ec1);
    Calib<1>::run(trans, lam2, lam1, Ec2);

    float A; int Kt = 0; int t, tend;
    if (role == 0) { A = __expf(inputs[(size_t)b * LL + lam1]); t = 1; tend = 1 + nfwd; }
    else           { A = (lam1 == col) ? 1.f : 0.f; t = 1 + nfwd + chunk * nch; tend = t + nch; }

    float R0[4], R1[4], R2[4];
    LDBLK(R0, t); LDBLK(R1, t + 8); LDBLK(R2, t + 16);
    for (;;) {
      if (t + 8 > tend) break;
      FCC_BLOCK8(R0); LDBLK(R0, t + 24); t += 8;
      if (t + 8 > tend) break;
      FCC_BLOCK8(R1); LDBLK(R1, t + 24); t += 8;
      if (t + 8 > tend) break;
      FCC_BLOCK8(R2); LDBLK(R2, t + 24); t += 8;
    }
    if (t < tend) {  // tail (<8 steps) — only possible for role 0
      float RT[4];
      LDBLK(RT, t);
      float eb[8];
      #pragma unroll
      for (int q = 0; q < 8; ++q) {
        float raw = bperm((q & 1) ? adO : adE, RT[q >> 1]);
        eb[q] = __expf(raw);
      }
      #pragma unroll
      for (int q = 0; q < 8; ++q) {
        if (t + q >= tend) break;
        if ((q & 1) == 0) { float part; STEP16(Ec1); A = eb[q] * xsum16(part); }
        else              { float part; STEP16(Ec2); A = eb[q] * xsum32(part); }
      }
    }
    // export (parity-aware label indexing)
    if (role == 0) {
      const int par = nfwd & 1;
      const int idx = par ? lam2 : lam1;
      const bool wr = par ? ((l & 16) == 0) : (l < 32);
      if (wr) P[OF_FWD + idx] = A;
      if (l == 0) P[OF_FWD + 32] = (float)Kt;
    } else {
      float* dst = P + (chunk == 0 ? OF_MA : OF_MB) + col * 33;
      if (l < 32) dst[lam1] = A;     // nch even -> lam1 layout
      if (l == 0) dst[32] = (float)Kt;
    }

  } else if (role == 1) {
    // ---------------- FCC backward vector scan (v^T <- v^T D_t M) --------
    __builtin_amdgcn_s_setprio(1);
    const int lam1 = l & 31;
    const int lam2 = (l & 15) | ((l >> 5) << 4);
    const int adE = lam2 * 4;
    const int adO = 128 + lam1 * 4;
    float E1T[16], E2T[16];
    E1T[0] = __expf(trans[lam1 * LL + lam2]);
    E2T[0] = __expf(trans[lam2 * LL + lam1]);
    CalibT<1>::run(trans, lam1, lam2, E1T);
    CalibT<1>::run(trans, lam2, lam1, E2T);

    float A = 1.f; int Kt = 0;
    int thi = lenm1, rem = nch;
    float R0[4], R1[4], R2[4];
    LDBLKD(R0, thi - 7); LDBLKD(R1, thi - 15); LDBLKD(R2, thi - 23);
    for (;;) {
      if (rem < 8) break;
      FCC_BWDBLK8(R0); LDBLKD(R0, thi - 31); thi -= 8; rem -= 8;
      if (rem < 8) break;
      FCC_BWDBLK8(R1); LDBLKD(R1, thi - 31); thi -= 8; rem -= 8;
      if (rem < 8) break;
      FCC_BWDBLK8(R2); LDBLKD(R2, thi - 31); thi -= 8; rem -= 8;
    }
    // nch even -> lam1 layout
    if (l < 32) P[OF_BWD + lam1] = A;
    if (l == 0) P[OF_BWD + 32] = (float)Kt;

  } else if (role == 2) {
    // ---------------- FAC forward half -----------------------------------
    __builtin_amdgcn_s_setprio(1);
    int tg[4];
    #pragma unroll
    for (int q = 0; q < 4; ++q) tg[q] = targets[b * SS + 4 * l + q];
    float ST[4], MVl[4];
    #pragma unroll
    for (int q = 0; q < 4; ++q) ST[q] = __expf(trans[tg[q] * LL + tg[q]]);
    MVl[0] = (l == 0) ? 0.f : __expf(trans[tg[0] * LL + targets[b * SS + 4 * l - 1]]);
    #pragma unroll
    for (int q = 1; q < 4; ++q) MVl[q] = __expf(trans[tg[q] * LL + tg[q - 1]]);
    int adA[4], adB[4];
    #pragma unroll
    for (int j = 0; j < 4; ++j) { adA[j] = tg[j] * 4; adB[j] = adA[j] + 128; }

    float A0 = (l == 0) ? __expf(inputs[(size_t)b * LL + tg[0]]) : 0.f;
    float A1 = 0.f, A2 = 0.f, A3 = 0.f;
    float m  = (l == 0) ? 0.f : NEGF;
    float MV0b;
    FAC_BOUNDARY();

    const int nbf = (Lsteps / 2) & ~7;
    const int nff = Lsteps - nbf;
    int t = 1; const int tend = 1 + nff;
    float R0[4], R1[4], R2[4];
    LDBLK(R0, 1); LDBLK(R1, 9); LDBLK(R2, 17);
    for (;;) {
      if (t + 8 > tend) break;
      FAC_BLOCK8(R0); LDBLK(R0, t + 24); t += 8;
      if (t + 8 > tend) break;
      FAC_BLOCK8(R1); LDBLK(R1, t + 24); t += 8;
      if (t + 8 > tend) break;
      FAC_BLOCK8(R2); LDBLK(R2, t + 24); t += 8;
    }
    if (t < tend) {  // tail
      float RT[4];
      LDBLK(RT, t);
      float E[8][4];
      #pragma unroll
      for (int r = 0; r < 8; ++r)
        #pragma unroll
        for (int j = 0; j < 4; ++j) {
          float raw = bperm((r & 1) ? adB[j] : adA[j], RT[r >> 1]);
          E[r][j] = __expf(raw);
        }
      #pragma unroll
      for (int r = 0; r < 8; ++r) {
        if (t + r >= tend) break;
        FAC_STEP(E[r][0], E[r][1], E[r][2], E[r][3]);
      }
    }
    P[OF_FACF + 4 * l + 0] = A0;
    P[OF_FACF + 4 * l + 1] = A1;
    P[OF_FACF + 4 * l + 2] = A2;
    P[OF_FACF + 4 * l + 3] = A3;
    P[OF_FACF + 256 + l]   = m;

  } else {
    // ---------------- FAC backward half (beta) ---------------------------
    __builtin_amdgcn_s_setprio(1);
    const int tl = tlen[b];
    const int fs = tl - 1;
    int tg[4];
    #pragma unroll
    for (int q = 0; q < 4; ++q) tg[q] = targets[b * SS + 4 * l + q];
    float ST[4], MVn[4];
    #pragma unroll
    for (int q = 0; q < 4; ++q) ST[q] = __expf(trans[tg[q] * LL + tg[q]]);
    MVn[0] = __expf(trans[tg[1] * LL + tg[0]]);
    MVn[1] = __expf(trans[tg[2] * LL + tg[1]]);
    MVn[2] = __expf(trans[tg[3] * LL + tg[2]]);
    int tgn3 = (l < 63) ? targets[b * SS + 4 * l + 4] : 0;
    MVn[3] = (l < 63) ? __expf(trans[tgn3 * LL + tg[3]]) : 0.f;
    int adA[4], adB[4];
    #pragma unroll
    for (int j = 0; j < 4; ++j) { adA[j] = tg[j] * 4; adB[j] = adA[j] + 128; }

    float A0 = (4 * l + 0 == fs) ? 1.f : 0.f;
    float A1 = (4 * l + 1 == fs) ? 1.f : 0.f;
    float A2 = (4 * l + 2 == fs) ? 1.f : 0.f;
    float A3 = (4 * l + 3 == fs) ? 1.f : 0.f;
    float m  = (l == (fs >> 2)) ? 0.f : NEGF;
    float MVn3b;
    FACB_BOUNDARY();

    const int nbf = (Lsteps / 2) & ~7;   // multiple of 8 -> no tail
    int thi = lenm1, rem = nbf;
    float R0[4], R1[4], R2[4];
    LDBLKD(R0, thi - 7); LDBLKD(R1, thi - 15); LDBLKD(R2, thi - 23);
    for (;;) {
      if (rem < 8) break;
      FACB_BLOCK8(R0); LDBLKD(R0, thi - 31); thi -= 8; rem -= 8;
      if (rem < 8) break;
      FACB_BLOCK8(R1); LDBLKD(R1, thi - 31); thi -= 8; rem -= 8;
      if (rem < 8) break;
      FACB_BLOCK8(R2); LDBLKD(R2, thi - 31); thi -= 8; rem -= 8;
    }
    P[OF_FACB + 4 * l + 0] = A0;
    P[OF_FACB + 4 * l + 1] = A1;
    P[OF_FACB + 4 * l + 2] = A2;
    P[OF_FACB + 4 * l + 3] = A3;
    P[OF_FACB + 256 + l]   = m;
  }
}

// ======================= combine ========================================

extern "C" __global__ __launch_bounds__(1024)
void asg_combine(const float* __restrict__ ws, float* __restrict__ out) {
  __shared__ float sd[TB];
  const int tid = (int)threadIdx.x;
  const int w = tid >> 6, l = tid & 63;

  for (int k = 0; k < 4; ++k) {
    const int b = w * 4 + k;
    const float* P = ws + (size_t)b * WSB;

    // ---- FCC: score = v^T * MB * MA * alpha ----
    float al  = (l < 32) ? P[OF_FWD + l] : 0.f;
    float Kacc = P[OF_FWD + 32];

    float KA = (l < 32) ? P[OF_MA + 33 * l + 32] : -3.0e38f;
    float Km = KA;
    for (int s = 1; s < 64; s <<= 1) Km = fmaxf(Km, __shfl_xor(Km, s));
    float wj = (l < 32) ? al * exp2f(KA - Km) : 0.f;
    float t1 = 0.f;
    for (int j = 0; j < 32; ++j) t1 += P[OF_MA + 33 * j + (l & 31)] * __shfl(wj, j);
    Kacc += Km;
    {
      float mx = t1;
      for (int s = 1; s < 64; s <<= 1) mx = fmaxf(mx, __shfl_xor(mx, s));
      if (mx > 0.f) {
        int ex = (int)((__float_as_uint(mx) >> 23) & 255) - 127;
        t1 = ldexpf(t1, -ex); Kacc += (float)ex;
      }
    }
    float KB = (l < 32) ? P[OF_MB + 33 * l + 32] : -3.0e38f;
    float Km2 = KB;
    for (int s = 1; s < 64; s <<= 1) Km2 = fmaxf(Km2, __shfl_xor(Km2, s));
    float w2 = (l < 32) ? t1 * exp2f(KB - Km2) : 0.f;
    float t2 = 0.f;
    for (int j = 0; j < 32; ++j) t2 += P[OF_MB + 33 * j + (l & 31)] * __shfl(w2, j);
    Kacc += Km2;
    {
      float mx = t2;
      for (int s = 1; s < 64; s <<= 1) mx = fmaxf(mx, __shfl_xor(mx, s));
      if (mx > 0.f) {
        int ex = (int)((__float_as_uint(mx) >> 23) & 255) - 127;
        t2 = ldexpf(t2, -ex); Kacc += (float)ex;
      }
    }
    float v = (l < 32) ? P[OF_BWD + l] : 0.f;
    Kacc += P[OF_BWD + 32];
    float sF = (l < 32) ? v * t2 : 0.f;
    for (int s = 1; s < 64; s <<= 1) sF += __shfl_xor(sF, s);
    float fcc = __logf(sF) + Kacc * LN2F;

    // ---- FAC: score = sum_s alpha[s] * beta[s] ----
    float pa = P[OF_FACF + 4 * l + 0] * P[OF_FACB + 4 * l + 0]
             + P[OF_FACF + 4 * l + 1] * P[OF_FACB + 4 * l + 1]
             + P[OF_FACF + 4 * l + 2] * P[OF_FACB + 4 * l + 2]
             + P[OF_FACF + 4 * l + 3] * P[OF_FACB + 4 * l + 3];
    float sc = P[OF_FACF + 256 + l] + P[OF_FACB + 256 + l];
    float Ms = sc;
    for (int s = 1; s < 64; s <<= 1) Ms = fmaxf(Ms, __shfl_xor(Ms, s));
    float pp = pa * exp2f(sc - Ms);
    for (int s = 1; s < 64; s <<= 1) pp += __shfl_xor(pp, s);
    float fac = __logf(pp) + Ms * LN2F;

    if (l == 0) sd[b] = fcc - fac;
  }
  __syncthreads();
  if (tid < TB) {
    float d = sd[tid];
    for (int s = 1; s < 64; s <<= 1) d += __shfl_xor(d, s);
    if (tid == 0) out[0] = d * (1.0f / TB);
  }
}

// ======================= launcher =======================================

extern "C" void kernel_launch(void* const* d_in, const int* in_sizes, int n_in,
                              void* d_out, int out_size, void* d_ws, size_t ws_size,
                              hipStream_t stream) {
  const float* trans   = (const float*)d_in[0];
  const float* inputs  = (const float*)d_in[1];
  const int*   targets = (const int*)d_in[2];
  const int*   ilen    = (const int*)d_in[3];
  const int*   tlen    = (const int*)d_in[4];
  float* out = (float*)d_out;
  float* ws  = (float*)d_ws;

  // 256 vector-scan blocks + 2 chunks x 32 basis columns x 64 batches
  asg_main<<<dim3(4 * TB + 2 * LL * TB), dim3(64), 0, stream>>>(
      trans, inputs, targets, ilen, tlen, ws);
  asg_combine<<<dim3(1), dim3(1024), 0, stream>>>(ws, out);
}

// Round 2
// 82.514 us; speedup vs baseline: 2.4736x; 2.1738x over previous
//
#include <hip/hip_runtime.h>
#include <math.h>

static constexpr int TB = 64;   // batch
static constexpr int LL = 32;   // labels
static constexpr int SS = 256;  // max target length
static constexpr int STRIDE_T = TB * LL;  // floats per time step (2048)

// ---- workspace layout (floats per batch) --------------------------------
static constexpr int OF_FWD  = 0;                 // 33: alpha[32] + K
static constexpr int OF_BWD  = 33;                // 33: v[32] + K
static constexpr int OF_FACF = 2178;              // 256 vals + 64 scales
static constexpr int OF_FACB = 2498;              // 256 vals + 64 scales
static constexpr int WSB     = 2818;              // per-batch stride (unchanged)

#define LN2F 0.69314718055994530942f
#define NEGF (-1e30f)

// raw barrier: waits LDS only (keeps helper global-load prefetch in flight)
#define BARX() { asm volatile("s_waitcnt lgkmcnt(0)" ::: "memory"); \
                 __builtin_amdgcn_s_barrier(); \
                 asm volatile("" ::: "memory"); }

// ---- DPP / cross-lane helpers ------------------------------------------
template<int CTL>
__device__ __forceinline__ float dpp_f(float x, float oldv) {
  return __int_as_float(__builtin_amdgcn_update_dpp(
      __float_as_int(oldv), __float_as_int(x), CTL, 0xF, 0xF, false));
}
template<int M>
__device__ __forceinline__ int rot_i(int x) {
  return __builtin_amdgcn_update_dpp(0, x, 0x120 + M, 0xF, 0xF, false); // row_ror:M
}

typedef unsigned uint2v __attribute__((ext_vector_type(2)));
__device__ __forceinline__ float xsum16(float x) {  // x[l] + x[l^16]
  uint2v r = __builtin_amdgcn_permlane16_swap(__float_as_uint(x), __float_as_uint(x), false, false);
  return __uint_as_float(r.x) + __uint_as_float(r.y);
}
__device__ __forceinline__ float xsum32(float x) {  // x[l] + x[l^32]
  uint2v r = __builtin_amdgcn_permlane32_swap(__float_as_uint(x), __float_as_uint(x), false, false);
  return __uint_as_float(r.x) + __uint_as_float(r.y);
}
__device__ __forceinline__ float bperm(int addr, float src) {  // pull lane addr>>2
  return __int_as_float(__builtin_amdgcn_ds_bpermute(addr, __float_as_int(src)));
}

// Self-calibrating coefficient load (rot_i matches row_ror:M exactly)
template<int M>
struct Calib {
  __device__ static __forceinline__ void run(const float* trans, int lam, int i, float* Ec) {
    Ec[M] = __expf(trans[i * LL + rot_i<M>(lam)]);
    Calib<M + 1>::run(trans, lam, i, Ec);
  }
};
template<> struct Calib<16> {
  __device__ static __forceinline__ void run(const float*, int, int, float*) {}
};
// Transposed variant: coefficient trans[rot(lam)][i]  (M^T matvec)
template<int M>
struct CalibT {
  __device__ static __forceinline__ void run(const float* trans, int lam, int i, float* Ec) {
    Ec[M] = __expf(trans[rot_i<M>(lam) * LL + i]);
    CalibT<M + 1>::run(trans, lam, i, Ec);
  }
};
template<> struct CalibT<16> {
  __device__ static __forceinline__ void run(const float*, int, int, float*) {}
};

// ---- fused rotate-multiply asm (1 instr per term) -----------------------
#define ROT_MUL(DST, SRC, COEF, ROT) \
  asm("v_mul_f32_dpp %0, %1, %2 row_ror:" #ROT " row_mask:0xf bank_mask:0xf" \
      : "=v"(DST) : "v"(SRC), "v"(COEF))
#define ROT_FMAC(ACC, SRC, COEF, ROT) \
  asm("v_fmac_f32_dpp %0, %1, %2 row_ror:" #ROT " row_mask:0xf bank_mask:0xf" \
      : "+v"(ACC) : "v"(SRC), "v"(COEF))

// matvec over 16-lane rows: part = sum_M EC[M] * rot_M(A); 4 indep chains
#define STEP16(EC) { \
  float a0 = EC[0] * A, a1, a2, a3; \
  ROT_MUL(a1, A, EC[1], 1); ROT_MUL(a2, A, EC[2], 2); ROT_MUL(a3, A, EC[3], 3); \
  ROT_FMAC(a0, A, EC[4], 4);  ROT_FMAC(a1, A, EC[5], 5); \
  ROT_FMAC(a2, A, EC[6], 6);  ROT_FMAC(a3, A, EC[7], 7); \
  ROT_FMAC(a0, A, EC[8], 8);  ROT_FMAC(a1, A, EC[9], 9); \
  ROT_FMAC(a2, A, EC[10], 10); ROT_FMAC(a3, A, EC[11], 11); \
  ROT_FMAC(a0, A, EC[12], 12); ROT_FMAC(a1, A, EC[13], 13); \
  ROT_FMAC(a2, A, EC[14], 14); ROT_FMAC(a3, A, EC[15], 15); \
  part = (a0 + a1) + (a2 + a3); }

// ======================= FCC chain ======================================

#define FCC_RENORM() { \
  unsigned uu = (unsigned)__builtin_amdgcn_readfirstlane((int)__float_as_uint(A)); \
  int ex = (int)((uu >> 23) & 255) - 127; \
  A = ldexpf(A, -ex); Kt += ex; }

#define FCC_CONSUME8(PB) { \
  float eb[8]; \
  _Pragma("unroll") for (int q = 0; q < 8; ++q) eb[q] = sE[PB][q][(q & 1) ? lam1 : lam2]; \
  { float part; STEP16(Ec1); A = eb[0] * xsum16(part); } \
  { float part; STEP16(Ec2); A = eb[1] * xsum32(part); } \
  { float part; STEP16(Ec1); A = eb[2] * xsum16(part); } \
  { float part; STEP16(Ec2); A = eb[3] * xsum32(part); } \
  { float part; STEP16(Ec1); A = eb[4] * xsum16(part); } \
  { float part; STEP16(Ec2); A = eb[5] * xsum32(part); } \
  { float part; STEP16(Ec1); A = eb[6] * xsum16(part); } \
  { float part; STEP16(Ec2); A = eb[7] * xsum32(part); } \
  FCC_RENORM(); }

#define FCC_TAIL(PB, CNT) { \
  float eb[8]; \
  _Pragma("unroll") for (int q = 0; q < 8; ++q) eb[q] = sE[PB][q][(q & 1) ? lam1 : lam2]; \
  _Pragma("unroll") for (int q = 0; q < 8; ++q) { \
    if (q >= (CNT)) break; \
    if ((q & 1) == 0) { float part; STEP16(Ec1); A = eb[q] * xsum16(part); } \
    else              { float part; STEP16(Ec2); A = eb[q] * xsum32(part); } } }

// backward (transpose): consumes rows 7..0; emission multiplies BEFORE matvec
#define FCC_BWDCON8(PB) { \
  float eb[8]; \
  _Pragma("unroll") for (int q = 0; q < 8; ++q) eb[q] = sE[PB][q][(q & 1) ? lam1 : lam2]; \
  { A *= eb[7]; float part; STEP16(E1T); A = xsum16(part); } \
  { A *= eb[6]; float part; STEP16(E2T); A = xsum32(part); } \
  { A *= eb[5]; float part; STEP16(E1T); A = xsum16(part); } \
  { A *= eb[4]; float part; STEP16(E2T); A = xsum32(part); } \
  { A *= eb[3]; float part; STEP16(E1T); A = xsum16(part); } \
  { A *= eb[2]; float part; STEP16(E2T); A = xsum32(part); } \
  { A *= eb[1]; float part; STEP16(E1T); A = xsum16(part); } \
  { A *= eb[0]; float part; STEP16(E2T); A = xsum32(part); } \
  FCC_RENORM(); }

// ======================= FAC chain ======================================

#define FAC_STEP(E0, E1, E2, E3) { \
  float ap = dpp_f<0x138>(A3, 0.f); /* wave_shr:1 */ \
  float n0 = (E0) * fmaf(MV0b,  ap, ST[0] * A0); \
  float n1 = (E1) * fmaf(MVl[1], A0, ST[1] * A1); \
  float n2 = (E2) * fmaf(MVl[2], A1, ST[2] * A2); \
  float n3 = (E3) * fmaf(MVl[3], A2, ST[3] * A3); \
  A0 = n0; A1 = n1; A2 = n2; A3 = n3; }

#define FAC_BOUNDARY() { \
  float maxA = fmaxf(fmaxf(A0, A1), fmaxf(A2, A3)); \
  if (maxA > 0.f) { \
    int ex = (int)((__float_as_uint(maxA) >> 23) & 255) - 127; \
    A0 = ldexpf(A0, -ex); A1 = ldexpf(A1, -ex); \
    A2 = ldexpf(A2, -ex); A3 = ldexpf(A3, -ex); \
    m += (float)ex; \
  } \
  float mp = dpp_f<0x138>(m, NEGF); m = (m == NEGF) ? mp : m; \
  mp = dpp_f<0x138>(m, NEGF);       m = (m == NEGF) ? mp : m; \
  mp = dpp_f<0x138>(m, NEGF); \
  float dlt = fminf(mp - m, 50.0f); \
  float Sin = exp2f(dlt); \
  MV0b = MVl[0] * Sin; }

#define FACF_CON8(PB) { \
  float4 Er[8]; \
  _Pragma("unroll") for (int r = 0; r < 8; ++r) Er[r] = sF[PB][r][l]; \
  _Pragma("unroll") for (int r = 0; r < 8; ++r) \
    FAC_STEP(Er[r].x, Er[r].y, Er[r].z, Er[r].w); \
  FAC_BOUNDARY(); }

#define FACF_TAIL(PB, CNT) { \
  float4 Er[8]; \
  _Pragma("unroll") for (int r = 0; r < 8; ++r) Er[r] = sF[PB][r][l]; \
  _Pragma("unroll") for (int r = 0; r < 8; ++r) { \
    if (r >= (CNT)) break; \
    FAC_STEP(Er[r].x, Er[r].y, Er[r].z, Er[r].w); } }

#define FACB_BOUNDARY() { \
  float maxA = fmaxf(fmaxf(A0, A1), fmaxf(A2, A3)); \
  if (maxA > 0.f) { \
    int ex = (int)((__float_as_uint(maxA) >> 23) & 255) - 127; \
    A0 = ldexpf(A0, -ex); A1 = ldexpf(A1, -ex); \
    A2 = ldexpf(A2, -ex); A3 = ldexpf(A3, -ex); \
    m += (float)ex; \
  } \
  float mp = dpp_f<0x130>(m, NEGF); m = (m == NEGF) ? mp : m; \
  mp = dpp_f<0x130>(m, NEGF);       m = (m == NEGF) ? mp : m; \
  mp = dpp_f<0x130>(m, NEGF); \
  float dlt = fminf(mp - m, 50.0f); \
  MVn3b = MVn[3] * exp2f(dlt); }

#define FACB_CON8(PB) { \
  float4 Er[8]; \
  _Pragma("unroll") for (int r = 0; r < 8; ++r) Er[r] = sF[PB][r][l]; \
  _Pragma("unroll") for (int i = 0; i < 8; ++i) { \
    const int q = 7 - i; \
    float en3 = dpp_f<0x130>(Er[q].x, 0.f); /* wave_shl:1 */ \
    float an  = dpp_f<0x130>(A0, 0.f); \
    float n0 = fmaf(Er[q].y * MVn[0], A1, Er[q].x * ST[0] * A0); \
    float n1 = fmaf(Er[q].z * MVn[1], A2, Er[q].y * ST[1] * A1); \
    float n2 = fmaf(Er[q].w * MVn[2], A3, Er[q].z * ST[2] * A2); \
    float n3 = fmaf(en3 * MVn3b,      an, Er[q].w * ST[3] * A3); \
    A0 = n0; A1 = n1; A2 = n2; A3 = n3; } \
  FACB_BOUNDARY(); }

// ======================= helper (producer) ==============================

// clamped global load of row-pair K for phase Q (per-lane, 2 rows via rowoff)
#define HLD(Q, K) ({ \
  int tt_ = (isfwd ? (1 + 8 * (Q)) : (lenm1 - 8 * (Q) - 7)) + 2 * (K) + rowoff; \
  tt_ = tt_ < 0 ? 0 : (tt_ > lenm1 ? lenm1 : tt_); \
  gpl[(size_t)tt_ * STRIDE_T]; })

#define PROD_FCC(PB, KK, RV) { sE[PB][2 * (KK) + rowoff][lam1] = __expf(RV); }

#define PROD_FAC(PB, KK, RV) { \
  float e_ = __expf(RV); \
  float4 E0_, E1_; \
  E0_.x = bperm(adA[0], e_); E0_.y = bperm(adA[1], e_); \
  E0_.z = bperm(adA[2], e_); E0_.w = bperm(adA[3], e_); \
  E1_.x = bperm(adB[0], e_); E1_.y = bperm(adB[1], e_); \
  E1_.z = bperm(adB[2], e_); E1_.w = bperm(adB[3], e_); \
  sF[PB][2 * (KK)][l]     = E0_; \
  sF[PB][2 * (KK) + 1][l] = E1_; }

// ======================= main kernel ====================================

extern "C" __global__ __launch_bounds__(192, 1)
void asg_main(const float* __restrict__ trans, const float* __restrict__ inputs,
              const int* __restrict__ targets, const int* __restrict__ ilen,
              const int* __restrict__ tlen, float* __restrict__ ws) {
  const int tid = (int)threadIdx.x;
  const int w = tid >> 6;        // 0 = chain, 1/2 = helpers
  const int l = tid & 63;
  const int lam1 = l & 31;
  const int lam2 = (l & 15) | ((l >> 5) << 4);
  const int rowoff = l >> 5;

  const int role = (int)blockIdx.x >> 6;  // 0 FCCfwd, 1 FCCbwd, 2 FACfwd, 3 FACbwd
  const int b    = (int)blockIdx.x & 63;

  const int len = ilen[b];
  const int lenm1 = len - 1;
  const int Lsteps = lenm1;
  const int nb = (Lsteps / 2) & ~7;        // bwd steps (multiple of 8)
  const int nf = Lsteps - nb;              // fwd steps (may have tail)
  const bool isfwd = (role == 0) || (role == 2);
  const int nsteps = isfwd ? nf : nb;
  const int nph = (nsteps + 7) >> 3;

  const float* gpl = inputs + (size_t)b * LL + lam1;
  float* P = ws + (size_t)b * WSB;

  __shared__ float  sE[2][8][32];   // FCC emission exp staging
  __shared__ float4 sF[2][8][64];   // FAC per-lane E staging

  if (w == 0) {
    // ================= chain wave ======================================
    __builtin_amdgcn_s_setprio(1);

    if (role == 0) {
      // ---- FCC forward vector scan ----
      float Ec1[16], Ec2[16];
      Ec1[0] = __expf(trans[lam2 * LL + lam1]);
      Ec2[0] = __expf(trans[lam1 * LL + lam2]);
      Calib<1>::run(trans, lam1, lam2, Ec1);
      Calib<1>::run(trans, lam2, lam1, Ec2);
      float A = __expf(inputs[(size_t)b * LL + lam1]);
      int Kt = 0;
      for (int p = 0; p < nph; p += 2) {
        BARX();
        { const int rem = nsteps - 8 * p;
          if (rem >= 8) { FCC_CONSUME8(0); } else { FCC_TAIL(0, rem); } }
        BARX();
        if (p + 1 < nph) {
          const int rem = nsteps - 8 * (p + 1);
          if (rem >= 8) { FCC_CONSUME8(1); } else { FCC_TAIL(1, rem); }
        }
      }
      const int par = nsteps & 1;
      const int idx = par ? lam2 : lam1;
      const bool wr = par ? ((l & 16) == 0) : (l < 32);
      if (wr) P[OF_FWD + idx] = A;
      if (l == 0) P[OF_FWD + 32] = (float)Kt;

    } else if (role == 1) {
      // ---- FCC backward (transpose) vector scan ----
      float E1T[16], E2T[16];
      E1T[0] = __expf(trans[lam1 * LL + lam2]);
      E2T[0] = __expf(trans[lam2 * LL + lam1]);
      CalibT<1>::run(trans, lam1, lam2, E1T);
      CalibT<1>::run(trans, lam2, lam1, E2T);
      float A = 1.f;
      int Kt = 0;
      for (int p = 0; p < nph; p += 2) {
        BARX();
        FCC_BWDCON8(0);
        BARX();
        if (p + 1 < nph) { FCC_BWDCON8(1); }
      }
      if (l < 32) P[OF_BWD + lam1] = A;        // nb even -> lam1 layout
      if (l == 0) P[OF_BWD + 32] = (float)Kt;

    } else if (role == 2) {
      // ---- FAC forward half ----
      int tg[4];
      #pragma unroll
      for (int q = 0; q < 4; ++q) tg[q] = targets[b * SS + 4 * l + q];
      float ST[4], MVl[4];
      #pragma unroll
      for (int q = 0; q < 4; ++q) ST[q] = __expf(trans[tg[q] * LL + tg[q]]);
      MVl[0] = (l == 0) ? 0.f : __expf(trans[tg[0] * LL + targets[b * SS + 4 * l - 1]]);
      #pragma unroll
      for (int q = 1; q < 4; ++q) MVl[q] = __expf(trans[tg[q] * LL + tg[q - 1]]);

      float A0 = (l == 0) ? __expf(inputs[(size_t)b * LL + tg[0]]) : 0.f;
      float A1 = 0.f, A2 = 0.f, A3 = 0.f;
      float m  = (l == 0) ? 0.f : NEGF;
      float MV0b;
      FAC_BOUNDARY();

      for (int p = 0; p < nph; p += 2) {
        BARX();
        { const int rem = nsteps - 8 * p;
          if (rem >= 8) { FACF_CON8(0); } else { FACF_TAIL(0, rem); } }
        BARX();
        if (p + 1 < nph) {
          const int rem = nsteps - 8 * (p + 1);
          if (rem >= 8) { FACF_CON8(1); } else { FACF_TAIL(1, rem); }
        }
      }
      P[OF_FACF + 4 * l + 0] = A0;
      P[OF_FACF + 4 * l + 1] = A1;
      P[OF_FACF + 4 * l + 2] = A2;
      P[OF_FACF + 4 * l + 3] = A3;
      P[OF_FACF + 256 + l]   = m;

    } else {
      // ---- FAC backward half (beta) ----
      const int tl = tlen[b];
      const int fs = tl - 1;
      int tg[4];
      #pragma unroll
      for (int q = 0; q < 4; ++q) tg[q] = targets[b * SS + 4 * l + q];
      float ST[4], MVn[4];
      #pragma unroll
      for (int q = 0; q < 4; ++q) ST[q] = __expf(trans[tg[q] * LL + tg[q]]);
      MVn[0] = __expf(trans[tg[1] * LL + tg[0]]);
      MVn[1] = __expf(trans[tg[2] * LL + tg[1]]);
      MVn[2] = __expf(trans[tg[3] * LL + tg[2]]);
      int tgn3 = (l < 63) ? targets[b * SS + 4 * l + 4] : 0;
      MVn[3] = (l < 63) ? __expf(trans[tgn3 * LL + tg[3]]) : 0.f;

      float A0 = (4 * l + 0 == fs) ? 1.f : 0.f;
      float A1 = (4 * l + 1 == fs) ? 1.f : 0.f;
      float A2 = (4 * l + 2 == fs) ? 1.f : 0.f;
      float A3 = (4 * l + 3 == fs) ? 1.f : 0.f;
      float m  = (l == (fs >> 2)) ? 0.f : NEGF;
      float MVn3b;
      FACB_BOUNDARY();

      for (int p = 0; p < nph; p += 2) {
        BARX();
        FACB_CON8(0);
        BARX();
        if (p + 1 < nph) { FACB_CON8(1); }
      }
      P[OF_FACB + 4 * l + 0] = A0;
      P[OF_FACB + 4 * l + 1] = A1;
      P[OF_FACB + 4 * l + 2] = A2;
      P[OF_FACB + 4 * l + 3] = A3;
      P[OF_FACB + 256 + l]   = m;
    }

  } else {
    // ================= helper waves (emission producers) ================
    const int kh = 2 * (w - 1);          // row-pair indices kh, kh+1
    const bool fac = (role >= 2);
    int adA[4] = {0, 0, 0, 0}, adB[4] = {0, 0, 0, 0};
    if (fac) {
      #pragma unroll
      for (int j = 0; j < 4; ++j) {
        int tg = targets[b * SS + 4 * l + j];
        adA[j] = tg * 4; adB[j] = adA[j] + 128;
      }
    }
    if (nph > 0) {
      // prologue: loads for phases 0..2, produce phase 0
      float p0a = HLD(0, kh), p0b = HLD(0, kh + 1);
      float sAa = HLD(1, kh), sAb = HLD(1, kh + 1);
      float sBa = HLD(2, kh), sBb = HLD(2, kh + 1);
      if (fac) { PROD_FAC(0, kh, p0a); PROD_FAC(0, kh + 1, p0b); }
      else     { PROD_FCC(0, kh, p0a); PROD_FCC(0, kh + 1, p0b); }

      for (int p = 0; p < nph; p += 2) {
        BARX();
        if (p + 1 < nph) {
          if (fac) { PROD_FAC(1, kh, sAa); PROD_FAC(1, kh + 1, sAb); }
          else     { PROD_FCC(1, kh, sAa); PROD_FCC(1, kh + 1, sAb); }
          sAa = HLD(p + 3, kh); sAb = HLD(p + 3, kh + 1);
        }
        BARX();
        if (p + 2 < nph) {
          if (fac) { PROD_FAC(0, kh, sBa); PROD_FAC(0, kh + 1, sBb); }
          else     { PROD_FCC(0, kh, sBa); PROD_FCC(0, kh + 1, sBb); }
          sBa = HLD(p + 4, kh); sBb = HLD(p + 4, kh + 1);
        }
      }
    }
  }
}

// ======================= combine ========================================

extern "C" __global__ __launch_bounds__(1024)
void asg_combine(const float* __restrict__ ws, float* __restrict__ out) {
  __shared__ float sd[TB];
  const int tid = (int)threadIdx.x;
  const int w = tid >> 6, l = tid & 63;

  for (int k = 0; k < 4; ++k) {
    const int b = w * 4 + k;
    const float* P = ws + (size_t)b * WSB;

    // ---- FCC: score = sum_label alpha[label] * v[label] ----
    float al = (l < 32) ? P[OF_FWD + l] : 0.f;
    float vv = (l < 32) ? P[OF_BWD + l] : 0.f;
    float s = al * vv;
    #pragma unroll
    for (int mm = 1; mm < 64; mm <<= 1) s += __shfl_xor(s, mm);
    float fcc = __logf(s) + (P[OF_FWD + 32] + P[OF_BWD + 32]) * LN2F;

    // ---- FAC: score = sum_s alpha[s] * beta[s] ----
    float pa = P[OF_FACF + 4 * l + 0] * P[OF_FACB + 4 * l + 0]
             + P[OF_FACF + 4 * l + 1] * P[OF_FACB + 4 * l + 1]
             + P[OF_FACF + 4 * l + 2] * P[OF_FACB + 4 * l + 2]
             + P[OF_FACF + 4 * l + 3] * P[OF_FACB + 4 * l + 3];
    float sc = P[OF_FACF + 256 + l] + P[OF_FACB + 256 + l];
    float Ms = sc;
    #pragma unroll
    for (int mm = 1; mm < 64; mm <<= 1) Ms = fmaxf(Ms, __shfl_xor(Ms, mm));
    float pp = pa * exp2f(sc - Ms);
    #pragma unroll
    for (int mm = 1; mm < 64; mm <<= 1) pp += __shfl_xor(pp, mm);
    float fac = __logf(pp) + Ms * LN2F;

    if (l == 0) sd[b] = fcc - fac;
  }
  __syncthreads();
  if (tid < TB) {
    float d = sd[tid];
    #pragma unroll
    for (int mm = 1; mm < 64; mm <<= 1) d += __shfl_xor(d, mm);
    if (tid == 0) out[0] = d * (1.0f / TB);
  }
}

// ======================= launcher =======================================

extern "C" void kernel_launch(void* const* d_in, const int* in_sizes, int n_in,
                              void* d_out, int out_size, void* d_ws, size_t ws_size,
                              hipStream_t stream) {
  const float* trans   = (const float*)d_in[0];
  const float* inputs  = (const float*)d_in[1];
  const int*   targets = (const int*)d_in[2];
  const int*   ilen    = (const int*)d_in[3];
  const int*   tlen    = (const int*)d_in[4];
  float* out = (float*)d_out;
  float* ws  = (float*)d_ws;

  // 4 roles x 64 batches, each block = 1 chain wave + 2 helper waves
  asg_main<<<dim3(4 * TB), dim3(192), 0, stream>>>(trans, inputs, targets, ilen, tlen, ws);
  asg_combine<<<dim3(1), dim3(1024), 0, stream>>>(ws, out);
}

// Round 3
// 81.906 us; speedup vs baseline: 2.4919x; 1.0074x over previous
//
#include <hip/hip_runtime.h>
#include <math.h>

static constexpr int TB = 64;   // batch
static constexpr int LL = 32;   // labels
static constexpr int SS = 256;  // max target length
static constexpr int STRIDE_T = TB * LL;  // floats per time step (2048)

// ---- workspace layout (floats per batch) --------------------------------
static constexpr int OF_FWD  = 0;                 // 33: alpha[32] + K
static constexpr int OF_BWD  = 33;                // 33: v[32] + K
static constexpr int OF_FACF = 2178;              // 256 vals + 64 scales
static constexpr int OF_FACB = 2498;              // 256 vals + 64 scales
static constexpr int WSB     = 2818;              // per-batch stride (unchanged)

#define LN2F 0.69314718055994530942f
#define NEGF (-1e30f)

// raw barrier: waits LDS only (keeps helper global-load prefetch in flight)
#define BARX() { asm volatile("s_waitcnt lgkmcnt(0)" ::: "memory"); \
                 __builtin_amdgcn_s_barrier(); \
                 asm volatile("" ::: "memory"); }

// ---- DPP / cross-lane helpers ------------------------------------------
template<int CTL>
__device__ __forceinline__ float dpp_f(float x, float oldv) {
  return __int_as_float(__builtin_amdgcn_update_dpp(
      __float_as_int(oldv), __float_as_int(x), CTL, 0xF, 0xF, false));
}
template<int M>
__device__ __forceinline__ int rot_i(int x) {
  return __builtin_amdgcn_update_dpp(0, x, 0x120 + M, 0xF, 0xF, false); // row_ror:M
}

typedef unsigned uint2v __attribute__((ext_vector_type(2)));
__device__ __forceinline__ float xsum16(float x) {  // x[l] + x[l^16]
  uint2v r = __builtin_amdgcn_permlane16_swap(__float_as_uint(x), __float_as_uint(x), false, false);
  return __uint_as_float(r.x) + __uint_as_float(r.y);
}
__device__ __forceinline__ float xsum32(float x) {  // x[l] + x[l^32]
  uint2v r = __builtin_amdgcn_permlane32_swap(__float_as_uint(x), __float_as_uint(x), false, false);
  return __uint_as_float(r.x) + __uint_as_float(r.y);
}
__device__ __forceinline__ float bperm(int addr, float src) {  // pull lane addr>>2
  return __int_as_float(__builtin_amdgcn_ds_bpermute(addr, __float_as_int(src)));
}

// Self-calibrating coefficient load (rot_i matches row_ror:M exactly)
template<int M>
struct Calib {
  __device__ static __forceinline__ void run(const float* trans, int lam, int i, float* Ec) {
    Ec[M] = __expf(trans[i * LL + rot_i<M>(lam)]);
    Calib<M + 1>::run(trans, lam, i, Ec);
  }
};
template<> struct Calib<16> {
  __device__ static __forceinline__ void run(const float*, int, int, float*) {}
};
// Transposed variant: coefficient trans[rot(lam)][i]  (M^T matvec)
template<int M>
struct CalibT {
  __device__ static __forceinline__ void run(const float* trans, int lam, int i, float* Ec) {
    Ec[M] = __expf(trans[rot_i<M>(lam) * LL + i]);
    CalibT<M + 1>::run(trans, lam, i, Ec);
  }
};
template<> struct CalibT<16> {
  __device__ static __forceinline__ void run(const float*, int, int, float*) {}
};

// ---- fused rotate-multiply asm (1 instr per term) -----------------------
#define ROT_MUL(DST, SRC, COEF, ROT) \
  asm("v_mul_f32_dpp %0, %1, %2 row_ror:" #ROT " row_mask:0xf bank_mask:0xf" \
      : "=v"(DST) : "v"(SRC), "v"(COEF))
#define ROT_FMAC(ACC, SRC, COEF, ROT) \
  asm("v_fmac_f32_dpp %0, %1, %2 row_ror:" #ROT " row_mask:0xf bank_mask:0xf" \
      : "+v"(ACC) : "v"(SRC), "v"(COEF))

// matvec over 16-lane rows: 8 indep chains of depth 2, then 3-level tree
#define STEP16(EC) { \
  float a0 = EC[0] * A, a1, a2, a3, a4, a5, a6, a7; \
  ROT_MUL(a1, A, EC[1], 1); ROT_MUL(a2, A, EC[2], 2); ROT_MUL(a3, A, EC[3], 3); \
  ROT_MUL(a4, A, EC[4], 4); ROT_MUL(a5, A, EC[5], 5); ROT_MUL(a6, A, EC[6], 6); \
  ROT_MUL(a7, A, EC[7], 7); \
  ROT_FMAC(a0, A, EC[8], 8);   ROT_FMAC(a1, A, EC[9], 9); \
  ROT_FMAC(a2, A, EC[10], 10); ROT_FMAC(a3, A, EC[11], 11); \
  ROT_FMAC(a4, A, EC[12], 12); ROT_FMAC(a5, A, EC[13], 13); \
  ROT_FMAC(a6, A, EC[14], 14); ROT_FMAC(a7, A, EC[15], 15); \
  part = ((a0 + a1) + (a2 + a3)) + ((a4 + a5) + (a6 + a7)); }

// ======================= FCC chain ======================================

#define FCC_RENORM() { \
  unsigned uu = (unsigned)__builtin_amdgcn_readfirstlane((int)__float_as_uint(A)); \
  int ex = (int)((uu >> 23) & 255) - 127; \
  A = ldexpf(A, -ex); Kt += ex; }

#define FCC_STEP_E(Q) { float part; STEP16(Ec1); A = eb[Q] * xsum16(part); }
#define FCC_STEP_O(Q) { float part; STEP16(Ec2); A = eb[Q] * xsum32(part); }

#define FCC_CONSUME16(PB) { \
  float eb[16]; \
  _Pragma("unroll") for (int q = 0; q < 16; ++q) eb[q] = sE[PB][q][(q & 1) ? lam1 : lam2]; \
  FCC_STEP_E(0); FCC_STEP_O(1); FCC_STEP_E(2); FCC_STEP_O(3); \
  FCC_STEP_E(4); FCC_STEP_O(5); FCC_STEP_E(6); FCC_STEP_O(7); \
  FCC_RENORM(); \
  FCC_STEP_E(8); FCC_STEP_O(9); FCC_STEP_E(10); FCC_STEP_O(11); \
  FCC_STEP_E(12); FCC_STEP_O(13); FCC_STEP_E(14); FCC_STEP_O(15); \
  FCC_RENORM(); }

#define FCC_TAIL16(PB, CNT) { \
  float eb[16]; \
  _Pragma("unroll") for (int q = 0; q < 16; ++q) eb[q] = sE[PB][q][(q & 1) ? lam1 : lam2]; \
  _Pragma("unroll") for (int q = 0; q < 16; ++q) { \
    if (q >= (CNT)) break; \
    if ((q & 1) == 0) { float part; STEP16(Ec1); A = eb[q] * xsum16(part); } \
    else              { float part; STEP16(Ec2); A = eb[q] * xsum32(part); } \
    if (q == 7) { FCC_RENORM(); } } }

// backward (transpose): consumes rows 15..0; emission multiplies BEFORE matvec
#define FCC_BSTEP_A(Q) { A *= eb[Q]; float part; STEP16(E1T); A = xsum16(part); }
#define FCC_BSTEP_B(Q) { A *= eb[Q]; float part; STEP16(E2T); A = xsum32(part); }

#define FCC_BWDCON16(PB) { \
  float eb[16]; \
  _Pragma("unroll") for (int q = 0; q < 16; ++q) eb[q] = sE[PB][q][(q & 1) ? lam1 : lam2]; \
  FCC_BSTEP_A(15); FCC_BSTEP_B(14); FCC_BSTEP_A(13); FCC_BSTEP_B(12); \
  FCC_BSTEP_A(11); FCC_BSTEP_B(10); FCC_BSTEP_A(9);  FCC_BSTEP_B(8); \
  FCC_RENORM(); \
  FCC_BSTEP_A(7);  FCC_BSTEP_B(6);  FCC_BSTEP_A(5);  FCC_BSTEP_B(4); \
  FCC_BSTEP_A(3);  FCC_BSTEP_B(2);  FCC_BSTEP_A(1);  FCC_BSTEP_B(0); \
  FCC_RENORM(); }

// ======================= FAC chain ======================================

#define FAC_STEP(E0, E1, E2, E3) { \
  float ap = dpp_f<0x138>(A3, 0.f); /* wave_shr:1 */ \
  float n0 = (E0) * fmaf(MV0b,  ap, ST[0] * A0); \
  float n1 = (E1) * fmaf(MVl[1], A0, ST[1] * A1); \
  float n2 = (E2) * fmaf(MVl[2], A1, ST[2] * A2); \
  float n3 = (E3) * fmaf(MVl[3], A2, ST[3] * A3); \
  A0 = n0; A1 = n1; A2 = n2; A3 = n3; }

#define FAC_BOUNDARY() { \
  float maxA = fmaxf(fmaxf(A0, A1), fmaxf(A2, A3)); \
  if (maxA > 0.f) { \
    int ex = (int)((__float_as_uint(maxA) >> 23) & 255) - 127; \
    A0 = ldexpf(A0, -ex); A1 = ldexpf(A1, -ex); \
    A2 = ldexpf(A2, -ex); A3 = ldexpf(A3, -ex); \
    m += (float)ex; \
  } \
  float mp = dpp_f<0x138>(m, NEGF); m = (m == NEGF) ? mp : m; \
  mp = dpp_f<0x138>(m, NEGF);       m = (m == NEGF) ? mp : m; \
  mp = dpp_f<0x138>(m, NEGF); \
  float dlt = fminf(mp - m, 50.0f); \
  float Sin = exp2f(dlt); \
  MV0b = MVl[0] * Sin; }

#define FACF_CON16(PB) { \
  float4 Er[16]; \
  _Pragma("unroll") for (int r = 0; r < 16; ++r) Er[r] = sF[PB][r][l]; \
  _Pragma("unroll") for (int r = 0; r < 8; ++r) \
    FAC_STEP(Er[r].x, Er[r].y, Er[r].z, Er[r].w); \
  FAC_BOUNDARY(); \
  _Pragma("unroll") for (int r = 8; r < 16; ++r) \
    FAC_STEP(Er[r].x, Er[r].y, Er[r].z, Er[r].w); \
  FAC_BOUNDARY(); }

#define FACF_TAIL16(PB, CNT) { \
  float4 Er[16]; \
  _Pragma("unroll") for (int r = 0; r < 16; ++r) Er[r] = sF[PB][r][l]; \
  _Pragma("unroll") for (int r = 0; r < 16; ++r) { \
    if (r >= (CNT)) break; \
    FAC_STEP(Er[r].x, Er[r].y, Er[r].z, Er[r].w); \
    if (r == 7) { FAC_BOUNDARY(); } } }

#define FACB_BOUNDARY() { \
  float maxA = fmaxf(fmaxf(A0, A1), fmaxf(A2, A3)); \
  if (maxA > 0.f) { \
    int ex = (int)((__float_as_uint(maxA) >> 23) & 255) - 127; \
    A0 = ldexpf(A0, -ex); A1 = ldexpf(A1, -ex); \
    A2 = ldexpf(A2, -ex); A3 = ldexpf(A3, -ex); \
    m += (float)ex; \
  } \
  float mp = dpp_f<0x130>(m, NEGF); m = (m == NEGF) ? mp : m; \
  mp = dpp_f<0x130>(m, NEGF);       m = (m == NEGF) ? mp : m; \
  mp = dpp_f<0x130>(m, NEGF); \
  float dlt = fminf(mp - m, 50.0f); \
  MVn3b = MVn[3] * exp2f(dlt); }

#define FACB_STEP(Q) { \
    float en3 = dpp_f<0x130>(Er[Q].x, 0.f); /* wave_shl:1 */ \
    float an  = dpp_f<0x130>(A0, 0.f); \
    float n0 = fmaf(Er[Q].y * MVn[0], A1, Er[Q].x * ST[0] * A0); \
    float n1 = fmaf(Er[Q].z * MVn[1], A2, Er[Q].y * ST[1] * A1); \
    float n2 = fmaf(Er[Q].w * MVn[2], A3, Er[Q].z * ST[2] * A2); \
    float n3 = fmaf(en3 * MVn3b,      an, Er[Q].w * ST[3] * A3); \
    A0 = n0; A1 = n1; A2 = n2; A3 = n3; }

#define FACB_CON16(PB) { \
  float4 Er[16]; \
  _Pragma("unroll") for (int r = 0; r < 16; ++r) Er[r] = sF[PB][r][l]; \
  FACB_STEP(15); FACB_STEP(14); FACB_STEP(13); FACB_STEP(12); \
  FACB_STEP(11); FACB_STEP(10); FACB_STEP(9);  FACB_STEP(8); \
  FACB_BOUNDARY(); \
  FACB_STEP(7);  FACB_STEP(6);  FACB_STEP(5);  FACB_STEP(4); \
  FACB_STEP(3);  FACB_STEP(2);  FACB_STEP(1);  FACB_STEP(0); \
  FACB_BOUNDARY(); }

// ======================= helper (producer) ==============================

// clamped global load of row-pair K (pair idx 0..7) for 16-row phase Q
#define HLD(Q, K) ({ \
  int tt_ = (isfwd ? (1 + 16 * (Q)) : (lenm1 - 16 * (Q) - 15)) + 2 * (K) + rowoff; \
  tt_ = tt_ < 0 ? 0 : (tt_ > lenm1 ? lenm1 : tt_); \
  gpl[(size_t)tt_ * STRIDE_T]; })

#define PROD_FCC(PB, KK, RV) { sE[PB][2 * (KK) + rowoff][lam1] = __expf(RV); }

#define PROD_FAC(PB, KK, RV) { \
  float e_ = __expf(RV); \
  float4 E0_, E1_; \
  E0_.x = bperm(adA[0], e_); E0_.y = bperm(adA[1], e_); \
  E0_.z = bperm(adA[2], e_); E0_.w = bperm(adA[3], e_); \
  E1_.x = bperm(adB[0], e_); E1_.y = bperm(adB[1], e_); \
  E1_.z = bperm(adB[2], e_); E1_.w = bperm(adB[3], e_); \
  sF[PB][2 * (KK)][l]     = E0_; \
  sF[PB][2 * (KK) + 1][l] = E1_; }

#define PRODUCE(PB, VA, VB) { \
  if (fac) { PROD_FAC(PB, kh, VA); PROD_FAC(PB, kh + 1, VB); } \
  else     { PROD_FCC(PB, kh, VA); PROD_FCC(PB, kh + 1, VB); } }

// ======================= main kernel ====================================

extern "C" __global__ __launch_bounds__(320, 1)
void asg_main(const float* __restrict__ trans, const float* __restrict__ inputs,
              const int* __restrict__ targets, const int* __restrict__ ilen,
              const int* __restrict__ tlen, float* __restrict__ ws) {
  const int tid = (int)threadIdx.x;
  const int w = tid >> 6;        // 0 = chain, 1..4 = helpers
  const int l = tid & 63;
  const int lam1 = l & 31;
  const int lam2 = (l & 15) | ((l >> 5) << 4);
  const int rowoff = l >> 5;

  const int role = (int)blockIdx.x >> 6;  // 0 FCCfwd, 1 FCCbwd, 2 FACfwd, 3 FACbwd
  const int b    = (int)blockIdx.x & 63;

  const int len = ilen[b];
  const int lenm1 = len - 1;
  const int Lsteps = lenm1;
  const int nb = (Lsteps / 2) & ~15;       // bwd steps (multiple of 16 -> no bwd tail)
  const int nf = Lsteps - nb;              // fwd steps (may have tail)
  const bool isfwd = (role == 0) || (role == 2);
  const int nsteps = isfwd ? nf : nb;
  const int nph = (nsteps + 15) >> 4;

  const float* gpl = inputs + (size_t)b * LL + lam1;
  float* P = ws + (size_t)b * WSB;

  __shared__ float  sE[2][16][32];   // FCC emission exp staging (4 KB)
  __shared__ float4 sF[2][16][64];   // FAC per-lane E staging  (32 KB)

  if (w == 0) {
    // ================= chain wave ======================================
    __builtin_amdgcn_s_setprio(1);

    if (role == 0) {
      // ---- FCC forward vector scan ----
      float Ec1[16], Ec2[16];
      Ec1[0] = __expf(trans[lam2 * LL + lam1]);
      Ec2[0] = __expf(trans[lam1 * LL + lam2]);
      Calib<1>::run(trans, lam1, lam2, Ec1);
      Calib<1>::run(trans, lam2, lam1, Ec2);
      float A = __expf(inputs[(size_t)b * LL + lam1]);
      int Kt = 0;
      for (int p = 0; p < nph; p += 2) {
        BARX();
        { const int rem = nsteps - 16 * p;
          if (rem >= 16) { FCC_CONSUME16(0); } else { FCC_TAIL16(0, rem); } }
        BARX();
        if (p + 1 < nph) {
          const int rem = nsteps - 16 * (p + 1);
          if (rem >= 16) { FCC_CONSUME16(1); } else { FCC_TAIL16(1, rem); }
        }
      }
      const int par = nsteps & 1;
      const int idx = par ? lam2 : lam1;
      const bool wr = par ? ((l & 16) == 0) : (l < 32);
      if (wr) P[OF_FWD + idx] = A;
      if (l == 0) P[OF_FWD + 32] = (float)Kt;

    } else if (role == 1) {
      // ---- FCC backward (transpose) vector scan ----
      float E1T[16], E2T[16];
      E1T[0] = __expf(trans[lam1 * LL + lam2]);
      E2T[0] = __expf(trans[lam2 * LL + lam1]);
      CalibT<1>::run(trans, lam1, lam2, E1T);
      CalibT<1>::run(trans, lam2, lam1, E2T);
      float A = 1.f;
      int Kt = 0;
      for (int p = 0; p < nph; p += 2) {
        BARX();
        FCC_BWDCON16(0);
        BARX();
        if (p + 1 < nph) { FCC_BWDCON16(1); }
      }
      if (l < 32) P[OF_BWD + lam1] = A;        // nb even -> lam1 layout
      if (l == 0) P[OF_BWD + 32] = (float)Kt;

    } else if (role == 2) {
      // ---- FAC forward half ----
      int tg[4];
      #pragma unroll
      for (int q = 0; q < 4; ++q) tg[q] = targets[b * SS + 4 * l + q];
      float ST[4], MVl[4];
      #pragma unroll
      for (int q = 0; q < 4; ++q) ST[q] = __expf(trans[tg[q] * LL + tg[q]]);
      MVl[0] = (l == 0) ? 0.f : __expf(trans[tg[0] * LL + targets[b * SS + 4 * l - 1]]);
      #pragma unroll
      for (int q = 1; q < 4; ++q) MVl[q] = __expf(trans[tg[q] * LL + tg[q - 1]]);

      float A0 = (l == 0) ? __expf(inputs[(size_t)b * LL + tg[0]]) : 0.f;
      float A1 = 0.f, A2 = 0.f, A3 = 0.f;
      float m  = (l == 0) ? 0.f : NEGF;
      float MV0b;
      FAC_BOUNDARY();

      for (int p = 0; p < nph; p += 2) {
        BARX();
        { const int rem = nsteps - 16 * p;
          if (rem >= 16) { FACF_CON16(0); } else { FACF_TAIL16(0, rem); } }
        BARX();
        if (p + 1 < nph) {
          const int rem = nsteps - 16 * (p + 1);
          if (rem >= 16) { FACF_CON16(1); } else { FACF_TAIL16(1, rem); }
        }
      }
      P[OF_FACF + 4 * l + 0] = A0;
      P[OF_FACF + 4 * l + 1] = A1;
      P[OF_FACF + 4 * l + 2] = A2;
      P[OF_FACF + 4 * l + 3] = A3;
      P[OF_FACF + 256 + l]   = m;

    } else {
      // ---- FAC backward half (beta) ----
      const int tl = tlen[b];
      const int fs = tl - 1;
      int tg[4];
      #pragma unroll
      for (int q = 0; q < 4; ++q) tg[q] = targets[b * SS + 4 * l + q];
      float ST[4], MVn[4];
      #pragma unroll
      for (int q = 0; q < 4; ++q) ST[q] = __expf(trans[tg[q] * LL + tg[q]]);
      MVn[0] = __expf(trans[tg[1] * LL + tg[0]]);
      MVn[1] = __expf(trans[tg[2] * LL + tg[1]]);
      MVn[2] = __expf(trans[tg[3] * LL + tg[2]]);
      int tgn3 = (l < 63) ? targets[b * SS + 4 * l + 4] : 0;
      MVn[3] = (l < 63) ? __expf(trans[tgn3 * LL + tg[3]]) : 0.f;

      float A0 = (4 * l + 0 == fs) ? 1.f : 0.f;
      float A1 = (4 * l + 1 == fs) ? 1.f : 0.f;
      float A2 = (4 * l + 2 == fs) ? 1.f : 0.f;
      float A3 = (4 * l + 3 == fs) ? 1.f : 0.f;
      float m  = (l == (fs >> 2)) ? 0.f : NEGF;
      float MVn3b;
      FACB_BOUNDARY();

      for (int p = 0; p < nph; p += 2) {
        BARX();
        FACB_CON16(0);
        BARX();
        if (p + 1 < nph) { FACB_CON16(1); }
      }
      P[OF_FACB + 4 * l + 0] = A0;
      P[OF_FACB + 4 * l + 1] = A1;
      P[OF_FACB + 4 * l + 2] = A2;
      P[OF_FACB + 4 * l + 3] = A3;
      P[OF_FACB + 256 + l]   = m;
    }

  } else {
    // ================= helper waves (emission producers) ================
    const int kh = 2 * (w - 1);          // pair indices kh, kh+1 (rows 4(w-1)..4(w-1)+3)
    const bool fac = (role >= 2);
    int adA[4] = {0, 0, 0, 0}, adB[4] = {0, 0, 0, 0};
    if (fac) {
      #pragma unroll
      for (int j = 0; j < 4; ++j) {
        int tg = targets[b * SS + 4 * l + j];
        adA[j] = tg * 4; adB[j] = adA[j] + 128;
      }
    }
    // 3-stage register prefetch queue: R1 = next produce, R2, R3 behind
    float R1a = HLD(0, kh), R1b = HLD(0, kh + 1);
    float R2a = HLD(1, kh), R2b = HLD(1, kh + 1);
    float R3a = HLD(2, kh), R3b = HLD(2, kh + 1);
    PRODUCE(0, R1a, R1b);                    // phase 0
    R1a = R2a; R1b = R2b; R2a = R3a; R2b = R3b;
    R3a = HLD(3, kh); R3b = HLD(3, kh + 1);

    for (int p = 0; p < nph; p += 2) {
      BARX();
      if (p + 1 < nph) {
        float Na = HLD(p + 4, kh), Nb = HLD(p + 4, kh + 1);  // issue first
        PRODUCE(1, R1a, R1b);                                // phase p+1
        R1a = R2a; R1b = R2b; R2a = R3a; R2b = R3b; R3a = Na; R3b = Nb;
      }
      BARX();
      if (p + 2 < nph) {
        float Na = HLD(p + 5, kh), Nb = HLD(p + 5, kh + 1);
        PRODUCE(0, R1a, R1b);                                // phase p+2
        R1a = R2a; R1b = R2b; R2a = R3a; R2b = R3b; R3a = Na; R3b = Nb;
      }
    }
  }
}

// ======================= combine ========================================

extern "C" __global__ __launch_bounds__(1024)
void asg_combine(const float* __restrict__ ws, float* __restrict__ out) {
  __shared__ float sd[TB];
  const int tid = (int)threadIdx.x;
  const int w = tid >> 6, l = tid & 63;

  for (int k = 0; k < 4; ++k) {
    const int b = w * 4 + k;
    const float* P = ws + (size_t)b * WSB;

    // ---- FCC: score = sum_label alpha[label] * v[label] ----
    float al = (l < 32) ? P[OF_FWD + l] : 0.f;
    float vv = (l < 32) ? P[OF_BWD + l] : 0.f;
    float s = al * vv;
    #pragma unroll
    for (int mm = 1; mm < 64; mm <<= 1) s += __shfl_xor(s, mm);
    float fcc = __logf(s) + (P[OF_FWD + 32] + P[OF_BWD + 32]) * LN2F;

    // ---- FAC: score = sum_s alpha[s] * beta[s] ----
    float pa = P[OF_FACF + 4 * l + 0] * P[OF_FACB + 4 * l + 0]
             + P[OF_FACF + 4 * l + 1] * P[OF_FACB + 4 * l + 1]
             + P[OF_FACF + 4 * l + 2] * P[OF_FACB + 4 * l + 2]
             + P[OF_FACF + 4 * l + 3] * P[OF_FACB + 4 * l + 3];
    float sc = P[OF_FACF + 256 + l] + P[OF_FACB + 256 + l];
    float Ms = sc;
    #pragma unroll
    for (int mm = 1; mm < 64; mm <<= 1) Ms = fmaxf(Ms, __shfl_xor(Ms, mm));
    float pp = pa * exp2f(sc - Ms);
    #pragma unroll
    for (int mm = 1; mm < 64; mm <<= 1) pp += __shfl_xor(pp, mm);
    float fac = __logf(pp) + Ms * LN2F;

    if (l == 0) sd[b] = fcc - fac;
  }
  __syncthreads();
  if (tid < TB) {
    float d = sd[tid];
    #pragma unroll
    for (int mm = 1; mm < 64; mm <<= 1) d += __shfl_xor(d, mm);
    if (tid == 0) out[0] = d * (1.0f / TB);
  }
}

// ======================= launcher =======================================

extern "C" void kernel_launch(void* const* d_in, const int* in_sizes, int n_in,
                              void* d_out, int out_size, void* d_ws, size_t ws_size,
                              hipStream_t stream) {
  const float* trans   = (const float*)d_in[0];
  const float* inputs  = (const float*)d_in[1];
  const int*   targets = (const int*)d_in[2];
  const int*   ilen    = (const int*)d_in[3];
  const int*   tlen    = (const int*)d_in[4];
  float* out = (float*)d_out;
  float* ws  = (float*)d_ws;

  // 4 roles x 64 batches, each block = 1 chain wave + 4 helper waves
  asg_main<<<dim3(4 * TB), dim3(320), 0, stream>>>(trans, inputs, targets, ilen, tlen, ws);
  asg_combine<<<dim3(1), dim3(1024), 0, stream>>>(ws, out);
}